// Round 3
// baseline (239.554 us; speedup 1.0000x reference)
//
#include <hip/hip_runtime.h>
#include <hip/hip_bf16.h>

// Problem: B=2, S=2048, D=256, H=8.
// out[b,h,s,:] = sum_{t<=s} exp( max(d2(s,t),0) / (2*gamma_h - 1e-6) ) * V[b,t,:]
// d2(s,t) = |Q_s|^2 + |K_t|^2 - 2 Q_s.K_t ; Q=p@Wq, K=p@Wk, V=e@Wv.
// Heads with equal gamma produce identical outputs -> dedupe by representative.
//
// R7: all MFMA operands pre-swizzled fragment-major (1KB contiguous b128 runs).
// R8: repack fused into GEMM epilogue; atomics -> split partials + reduce. 136us.
// R9: TSPLIT=8 regressed (+4.6us): flash per-block work is tiny, duplicating
//     per-block fixed costs (Q frags, partial stores) + 34MB extra traffic
//     beat the occupancy gain.  -> revert to TSPLIT=4.
// R10: fuse reduce/broadcast INTO flash via last-done-block (decoupled
//     lookback pattern): per-(b,st) counter in ws; 4th arriver sums the
//     min(TSPLIT,n_tiles) partial slabs and writes all 8 head copies.
//     Removes 1 launch + the serial ~16us reduce tail (now overlapped).

#define BB   2
#define SS   2048
#define DD   256
#define HH   8
#define BSR  (BB*SS)        // 4096 rows
#define TSPLIT 4

typedef __bf16 bf16_t;
typedef __bf16 bf16x8 __attribute__((ext_vector_type(8)));
typedef float  f32x4  __attribute__((ext_vector_type(4)));

static __device__ __forceinline__ f32x4 mfma16(bf16x8 a, bf16x8 b, f32x4 c) {
    return __builtin_amdgcn_mfma_f32_16x16x32_bf16(a, b, c, 0, 0, 0);
}

// ---------------------------------------------------------------------------
// K0: W -> fragment-major WF (hi/lo split), plus q2/k2/cnt zeroing (block 48).
// WF chunk (g16 in [0,16), kc in [0,8)) holds 512 elems at ((g16*8+kc)*512):
// position u*8+j = W^T[n = g16*16 + (u&15)][k = kc*32 + (u>>4)*8 + j].
// gemm's B-frag load is then base + lane*8 : contiguous 1KB per wave.
// ---------------------------------------------------------------------------
__global__ __launch_bounds__(256) void att_wtrans(
    const float* __restrict__ Wq, const float* __restrict__ Wk,
    const float* __restrict__ Wv,
    bf16_t* __restrict__ WFq_h, bf16_t* __restrict__ WFq_l,
    bf16_t* __restrict__ WFk_h, bf16_t* __restrict__ WFk_l,
    bf16_t* __restrict__ WFv, float* __restrict__ q2, float* __restrict__ k2,
    unsigned* __restrict__ cnt)
{
    __shared__ float tT[64][68];    // [n_local][k_local], pad 68
    const int tid = threadIdx.x;
    if (blockIdx.x == 48) {         // zero q2/k2 (gemm accumulates atomically)
        for (int i = tid; i < BSR; i += 256) { q2[i] = 0.f; k2[i] = 0.f; }
        for (int i = tid; i < BB * 64; i += 256) cnt[i] = 0u;
        return;
    }
    const int mat = blockIdx.x >> 4;        // 0=Wq 1=Wk 2=Wv
    const int tl  = blockIdx.x & 15;
    const int tr  = (tl >> 2) * 64, tc = (tl & 3) * 64;  // k-range, n-range
    const float* W = (mat == 0) ? Wq : ((mat == 1) ? Wk : Wv);

    // load W[k][n] tile rows coalesced, scatter transposed into LDS
#pragma unroll
    for (int i = 0; i < 4; ++i) {
        const int fidx = i * 256 + tid;     // [0,1024) float4 units
        const int r  = fidx >> 4;           // k_local
        const int c4 = fidx & 15;           // n_local/4
        const float4 v = *(const float4*)(W + (size_t)(tr + r) * DD + tc + c4 * 4);
        tT[c4 * 4 + 0][r] = v.x; tT[c4 * 4 + 1][r] = v.y;
        tT[c4 * 4 + 2][r] = v.z; tT[c4 * 4 + 3][r] = v.w;
    }
    __syncthreads();

#pragma unroll
    for (int i = 0; i < 2; ++i) {
        const int uidx  = i * 256 + tid;    // [0,512) 16B units
        const int chunk = uidx >> 6;        // kc_l(2) x c16(4)
        const int kc_l  = chunk >> 2, c16 = chunk & 3;
        const int u = uidx & 63, m16 = u & 15, quad = u >> 4;
        const float* src = &tT[c16 * 16 + m16][kc_l * 32 + quad * 8];
        const float4 a = *(const float4*)src;
        const float4 bq = *(const float4*)(src + 4);
        const float f[8] = {a.x, a.y, a.z, a.w, bq.x, bq.y, bq.z, bq.w};
        bf16x8 hi, lo;
#pragma unroll
        for (int j = 0; j < 8; ++j) {
            const bf16_t h = (bf16_t)f[j];
            hi[j] = h; lo[j] = (bf16_t)(f[j] - (float)h);
        }
        const int g16 = (tc >> 4) + c16;
        const int kcg = (tr >> 5) + kc_l;
        const size_t off = ((size_t)(g16 * 8 + kcg)) * 512 + (size_t)u * 8;
        if (mat == 0)      { *(bf16x8*)(WFq_h + off) = hi; *(bf16x8*)(WFq_l + off) = lo; }
        else if (mat == 1) { *(bf16x8*)(WFk_h + off) = hi; *(bf16x8*)(WFk_l + off) = lo; }
        else               { *(bf16x8*)(WFv + off)  = hi; }
    }
}

// ---------------------------------------------------------------------------
// K1: fused QKV projection via MFMA + DIRECT fragment-major epilogue.
// Block = 256 thr, 16 rows x 64 n-cols (4-way n-split in grid).
// The 16x64 output tile is exactly:
//   QF : tile st=sl/32, chunks (mt=(sl>>4)&1, kc=nb*2+{0,1})   (2 full chunks)
//   KF : tile tt=sl/64, chunks (w4=(sl>>4)&3, kc=nb*2+{0,1})   (2 full chunks)
//   VF : tile tt, chunks (w=nb, kc2=(sl>>5)&1, nt=0..3), u-half uh=(sl>>4)&1
// so the epilogue stages acc f32 in LDS and stores fragments directly.
// q2/k2 via shuffle + atomicAdd partials.
// ---------------------------------------------------------------------------
__global__ __launch_bounds__(256, 2) void att_gemm_qkv(
    const float* __restrict__ p, const float* __restrict__ e,
    const bf16_t* __restrict__ WFq_h, const bf16_t* __restrict__ WFq_l,
    const bf16_t* __restrict__ WFk_h, const bf16_t* __restrict__ WFk_l,
    const bf16_t* __restrict__ WFv,
    bf16_t* __restrict__ QFh, bf16_t* __restrict__ QFl,
    bf16_t* __restrict__ KFh, bf16_t* __restrict__ KFl,
    bf16_t* __restrict__ VF, float* __restrict__ q2, float* __restrict__ k2)
{
    __shared__ float pL[16][264];
    __shared__ float eL[16][264];
    __shared__ float fQ[16][68];
    __shared__ float fK[16][68];
    __shared__ float fV[16][68];

    const int tid  = threadIdx.x;
    const int w    = tid >> 6;
    const int lane = tid & 63;
    const int m16  = lane & 15;
    const int quad = lane >> 4;
    const int row0 = (blockIdx.x >> 2) * 16;
    const int nb   = blockIdx.x & 3;

    // stage p/e tiles (16 rows x 256 cols), coalesced
#pragma unroll
    for (int i = 0; i < 4; ++i) {
        const int fidx = i * 256 + tid;     // [0,1024) float4
        const int r  = fidx >> 6;
        const int c4 = fidx & 63;
        const float4 pv = *(const float4*)(p + (size_t)(row0 + r) * DD + c4 * 4);
        const float4 ev = *(const float4*)(e + (size_t)(row0 + r) * DD + c4 * 4);
        *(float4*)&pL[r][c4 * 4] = pv;
        *(float4*)&eL[r][c4 * 4] = ev;
    }
    __syncthreads();

    f32x4 aQ = f32x4{0.f, 0.f, 0.f, 0.f};
    f32x4 aK = f32x4{0.f, 0.f, 0.f, 0.f};
    f32x4 aV = f32x4{0.f, 0.f, 0.f, 0.f};

#pragma unroll 2
    for (int kc = 0; kc < 8; ++kc) {
        const float* ps = &pL[m16][kc * 32 + quad * 8];
        const float* es = &eL[m16][kc * 32 + quad * 8];
        const float4 p0 = *(const float4*)ps;
        const float4 p1 = *(const float4*)(ps + 4);
        const float4 e0 = *(const float4*)es;
        const float4 e1 = *(const float4*)(es + 4);
        const float pa[8] = {p0.x, p0.y, p0.z, p0.w, p1.x, p1.y, p1.z, p1.w};
        const float ea[8] = {e0.x, e0.y, e0.z, e0.w, e1.x, e1.y, e1.z, e1.w};
        bf16x8 aph, apl, aeb;
#pragma unroll
        for (int j = 0; j < 8; ++j) {
            const bf16_t h = (bf16_t)pa[j];
            aph[j] = h;
            apl[j] = (bf16_t)(pa[j] - (float)h);
            aeb[j] = (bf16_t)ea[j];
        }
        const size_t wo = ((size_t)((nb * 4 + w) * 8 + kc)) * 512 + (size_t)lane * 8;
        const bf16x8 bqh = *(const bf16x8*)(WFq_h + wo);
        const bf16x8 bql = *(const bf16x8*)(WFq_l + wo);
        const bf16x8 bkh = *(const bf16x8*)(WFk_h + wo);
        const bf16x8 bkl = *(const bf16x8*)(WFk_l + wo);
        const bf16x8 bv  = *(const bf16x8*)(WFv + wo);
        aQ = mfma16(aph, bqh, aQ);
        aQ = mfma16(apl, bqh, aQ);
        aQ = mfma16(aph, bql, aQ);
        aK = mfma16(aph, bkh, aK);
        aK = mfma16(apl, bkh, aK);
        aK = mfma16(aph, bkl, aK);
        aV = mfma16(aeb, bv, aV);
    }

    // stage accumulators f32 into LDS for the fragment transpose
#pragma unroll
    for (int r = 0; r < 4; ++r) {
        const int rl = quad * 4 + r;          // C/D row = quad*4+reg
        fQ[rl][w * 16 + m16] = aQ[r];
        fK[rl][w * 16 + m16] = aK[r];
        fV[rl][w * 16 + m16] = aV[r];
    }

    // q2/k2 row-norm partials (from f32 accumulators)
#pragma unroll
    for (int r = 0; r < 4; ++r) {
        float vq = aQ[r] * aQ[r], vk = aK[r] * aK[r];
#pragma unroll
        for (int off = 8; off >= 1; off >>= 1) {
            vq += __shfl_xor(vq, off);
            vk += __shfl_xor(vk, off);
        }
        if (m16 == 0) {
            atomicAdd(q2 + row0 + quad * 4 + r, vq);
            atomicAdd(k2 + row0 + quad * 4 + r, vk);
        }
    }

    __syncthreads();

    const int b   = row0 >> 11;
    const int sl  = row0 & 2047;
    const int tt  = sl >> 6;
    const int st  = sl >> 5;
    const int w4  = (sl >> 4) & 3;   // KF row-group
    const int mt  = (sl >> 4) & 1;   // QF row-group
    const int kc2 = (sl >> 5) & 1;   // VF t-half
    const int uh  = (sl >> 4) & 1;   // VF u-half

    if (w < 2) {
        // QF chunk kc = nb*2 + w  (hi + lo)
        const int cl = w;
        const float* src = &fQ[m16][cl * 32 + quad * 8];
        const float4 a = *(const float4*)src;
        const float4 c = *(const float4*)(src + 4);
        const float f[8] = {a.x, a.y, a.z, a.w, c.x, c.y, c.z, c.w};
        bf16x8 hi, lo;
#pragma unroll
        for (int j = 0; j < 8; ++j) {
            const bf16_t h = (bf16_t)f[j];
            hi[j] = h; lo[j] = (bf16_t)(f[j] - (float)h);
        }
        const size_t off = ((size_t)(b * 64 + st)) * 8192
                         + (size_t)(mt * 8 + nb * 2 + cl) * 512 + (size_t)lane * 8;
        *(bf16x8*)(QFh + off) = hi; *(bf16x8*)(QFl + off) = lo;
    } else {
        // KF chunk kc = nb*2 + (w-2)  (hi + lo)
        const int cl = w - 2;
        const float* src = &fK[m16][cl * 32 + quad * 8];
        const float4 a = *(const float4*)src;
        const float4 c = *(const float4*)(src + 4);
        const float f[8] = {a.x, a.y, a.z, a.w, c.x, c.y, c.z, c.w};
        bf16x8 hi, lo;
#pragma unroll
        for (int j = 0; j < 8; ++j) {
            const bf16_t h = (bf16_t)f[j];
            hi[j] = h; lo[j] = (bf16_t)(f[j] - (float)h);
        }
        const size_t off = ((size_t)(b * 32 + tt)) * 16384
                         + (size_t)(w4 * 8 + nb * 2 + cl) * 512 + (size_t)lane * 8;
        *(bf16x8*)(KFh + off) = hi; *(bf16x8*)(KFl + off) = lo;
    }

    // VF half-chunks: wave w handles nt=w with lanes 0..31 (u-half uh)
    if (lane < 32) {
        const int nt  = w;
        const int u   = uh * 32 + lane;
        const int tl0 = (lane >> 4) * 8;     // t_local base within block rows
        bf16x8 vb;
#pragma unroll
        for (int j = 0; j < 8; ++j)
            vb[j] = (bf16_t)fV[tl0 + j][nt * 16 + (lane & 15)];
        const size_t off = ((size_t)(b * 32 + tt)) * 16384
                         + (size_t)(nb * 8 + kc2 * 4 + nt) * 512 + (size_t)u * 8;
        *(bf16x8*)(VF + off) = vb;
    }
}

// ---------------------------------------------------------------------------
// K2: flash-style causal pass + FUSED cross-split reduction/broadcast.
// Grid = 256 blocks (32 pairs x 4 splits x 2 b) decoded so bid&7 == split*2+b:
// each XCD hosts one (split,b) class; K/V working set (~384KB) fits its L2.
// All splits write f32 partials to ws; after a block's h-loop for an s-tile,
// it increments cnt[b][st] (release fence).  The TSPLIT-th arriver (acquire
// fence) sums the min(TSPLIT,n_tiles) live slabs and writes every head copy.
// Non-blocking: no spin, no deadlock; add order == R8 (bit-identical out).
// ---------------------------------------------------------------------------
__global__ __launch_bounds__(256, 2) void att_flash(
    const bf16_t* __restrict__ QFh, const bf16_t* __restrict__ QFl,
    const bf16_t* __restrict__ KFh, const bf16_t* __restrict__ KFl,
    const bf16_t* __restrict__ VF, const float* __restrict__ q2,
    const float* __restrict__ k2, const float* __restrict__ gamma,
    float* __restrict__ part, unsigned* __restrict__ cnt,
    float* __restrict__ out)
{
    __shared__ bf16_t Pb[2][32][72];
    __shared__ int lastFlag;

    const int tid   = threadIdx.x;
    const int pair  = blockIdx.x >> 3;     // 0..31
    const int sub   = blockIdx.x & 7;      // == xcd class
    const int split = sub >> 1;            // 0..3
    const int b     = sub & 1;
    const int wave  = tid >> 6;
    const int lane  = tid & 63;
    const int m16   = lane & 15;
    const int quad  = lane >> 4;

    float g[8];
#pragma unroll
    for (int h = 0; h < 8; ++h) g[h] = gamma[h];

    int pb = 0;

    for (int half = 0; half < 2; ++half) {
        const int st = half ? (63 - pair) : pair;
        const int s0 = st * 32;
        const int n_tiles = (s0 + 31) / 64 + 1;
        const bool active = (split < n_tiles);

        if (active) {
            // Q fragments -> registers, contiguous chunk loads.
            bf16x8 aQh[2][8], aQl[2][8];
            const size_t qtile = ((size_t)(b * 64 + st)) * 8192 + (size_t)lane * 8;
#pragma unroll
            for (int mt = 0; mt < 2; ++mt)
#pragma unroll
                for (int kc = 0; kc < 8; ++kc) {
                    const size_t base = qtile + (size_t)(mt * 8 + kc) * 512;
                    aQh[mt][kc] = *(const bf16x8*)(QFh + base);
                    aQl[mt][kc] = *(const bf16x8*)(QFl + base);
                }

            float q2r[2][4];
#pragma unroll
            for (int mt = 0; mt < 2; ++mt)
#pragma unroll
                for (int r = 0; r < 4; ++r)
                    q2r[mt][r] = q2[b * SS + s0 + mt * 16 + quad * 4 + r];

            for (int h = 0; h < HH; ++h) {
                int rep = 0;
                while (g[rep] != g[h]) ++rep;
                if (rep != h) continue;
                const float cexp = 1.0f / (2.0f * g[h] - 1e-6f);

                f32x4 O[2][4];
#pragma unroll
                for (int mt = 0; mt < 2; ++mt)
#pragma unroll
                    for (int nt = 0; nt < 4; ++nt)
                        O[mt][nt] = f32x4{0.f, 0.f, 0.f, 0.f};

                for (int ti = split; ti < n_tiles; ti += TSPLIT) {
                    const int t0 = ti * 64;
                    const int tg = t0 + wave * 16 + m16;
                    const size_t tile = ((size_t)(b * 32 + ti)) * 16384
                                      + (size_t)wave * 4096 + (size_t)lane * 8;

                    // V prefetch (contiguous chunks; overlaps scores+barrier)
                    bf16x8 vf[2][4];
#pragma unroll
                    for (int kc2 = 0; kc2 < 2; ++kc2)
#pragma unroll
                        for (int nt = 0; nt < 4; ++nt)
                            vf[kc2][nt] = *(const bf16x8*)(
                                VF + tile + (size_t)(kc2 * 4 + nt) * 512);
                    const float k2v = k2[b * SS + tg];

                    // scores: S = Qh.Kh + Ql.Kh + Qh.Kl (fp32 acc)
                    f32x4 acc0 = f32x4{0.f, 0.f, 0.f, 0.f};
                    f32x4 acc1 = f32x4{0.f, 0.f, 0.f, 0.f};
                    __builtin_amdgcn_s_setprio(1);
#pragma unroll
                    for (int kc = 0; kc < 8; ++kc) {
                        const bf16x8 bh = *(const bf16x8*)(KFh + tile + (size_t)kc * 512);
                        const bf16x8 bl = *(const bf16x8*)(KFl + tile + (size_t)kc * 512);
                        acc0 = mfma16(aQh[0][kc], bh, acc0);
                        acc1 = mfma16(aQh[1][kc], bh, acc1);
                        acc0 = mfma16(aQl[0][kc], bh, acc0);
                        acc1 = mfma16(aQl[1][kc], bh, acc1);
                        acc0 = mfma16(aQh[0][kc], bl, acc0);
                        acc1 = mfma16(aQh[1][kc], bl, acc1);
                    }
                    __builtin_amdgcn_s_setprio(0);

#pragma unroll
                    for (int mt = 0; mt < 2; ++mt) {
#pragma unroll
                        for (int r = 0; r < 4; ++r) {
                            const int sl = mt * 16 + quad * 4 + r;
                            const int sg = s0 + sl;
                            const float dotv = mt ? acc1[r] : acc0[r];
                            float d2 = q2r[mt][r] + k2v - 2.0f * dotv;
                            d2 = fmaxf(d2, 0.0f);
                            const float wgt = (tg <= sg) ? __expf(cexp * d2) : 0.0f;
                            Pb[pb][sl][wave * 16 + m16] = (bf16_t)wgt;
                        }
                    }
                    __syncthreads();

                    // PV: O += P @ V (V already in registers)
                    __builtin_amdgcn_s_setprio(1);
#pragma unroll
                    for (int kc2 = 0; kc2 < 2; ++kc2) {
                        const bf16x8 pa0 = *(const bf16x8*)&Pb[pb][m16][kc2 * 32 + quad * 8];
                        const bf16x8 pa1 = *(const bf16x8*)&Pb[pb][m16 + 16][kc2 * 32 + quad * 8];
#pragma unroll
                        for (int nt = 0; nt < 4; ++nt) {
                            O[0][nt] = mfma16(pa0, vf[kc2][nt], O[0][nt]);
                            O[1][nt] = mfma16(pa1, vf[kc2][nt], O[1][nt]);
                        }
                    }
                    __builtin_amdgcn_s_setprio(0);
                    pb ^= 1;
                }

                // store this split's partial (f32) for (b, h, s-tile)
                float* dst = part + (((size_t)split * BB + b) * HH + h) * (size_t)SS * DD
                           + (size_t)s0 * DD;
#pragma unroll
                for (int mt = 0; mt < 2; ++mt)
#pragma unroll
                    for (int nt = 0; nt < 4; ++nt)
#pragma unroll
                        for (int r = 0; r < 4; ++r)
                            dst[(size_t)(mt * 16 + quad * 4 + r) * DD
                                + wave * 64 + nt * 16 + m16] = O[mt][nt][r];
            }
        }

        // ---- cross-split completion protocol for (b, st) ----
        __syncthreads();                    // drains all waves' stores (vmcnt0)
        if (tid == 0) {
            __threadfence();                // release: partials device-visible
            const unsigned prev = atomicAdd(&cnt[b * 64 + st], 1u);
            lastFlag = (prev == TSPLIT - 1) ? 1 : 0;
        }
        __syncthreads();

        if (lastFlag) {
            __threadfence();                // acquire: see other XCDs' partials
            const int kmax = (n_tiles < TSPLIT) ? n_tiles : TSPLIT;
            // 32 rows x 256 cols f32 = 2048 float4 units; 8 per thread
#pragma unroll
            for (int j = 0; j < 8; ++j) {
                const int f4  = j * 256 + tid;
                const int row = f4 >> 6, c4 = f4 & 63;
                const size_t rowoff = (size_t)(s0 + row) * DD + (size_t)c4 * 4;
                float4 s{0.f, 0.f, 0.f, 0.f};
                int lastr = -1;
                for (int hq = 0; hq < HH; ++hq) {
                    int rep = 0;
                    while (g[rep] != g[hq]) ++rep;
                    if (rep != lastr) {
                        s = float4{0.f, 0.f, 0.f, 0.f};
                        for (int k = 0; k < kmax; ++k) {
                            const float4 v = *(const float4*)(
                                part + (((size_t)k * BB + b) * HH + rep) * (size_t)SS * DD
                                     + rowoff);
                            s.x += v.x; s.y += v.y; s.z += v.z; s.w += v.w;
                        }
                        lastr = rep;
                    }
                    *(float4*)(out + ((size_t)(b * HH + hq) * SS) * DD + rowoff) = s;
                }
            }
        }
    }
}

extern "C" void kernel_launch(void* const* d_in, const int* in_sizes, int n_in,
                              void* d_out, int out_size, void* d_ws, size_t ws_size,
                              hipStream_t stream) {
    (void)in_sizes; (void)n_in; (void)out_size; (void)ws_size;
    // inputs: 0=x (unused), 1=e, 2=p, 3=W_q, 4=W_k, 5=W_v, 6=gamma
    const float* e     = (const float*)d_in[1];
    const float* p     = (const float*)d_in[2];
    const float* Wq    = (const float*)d_in[3];
    const float* Wk    = (const float*)d_in[4];
    const float* Wv    = (const float*)d_in[5];
    const float* gamma = (const float*)d_in[6];

    const size_t NROW = (size_t)BSR * DD;   // 1048576 elements
    bf16_t* WFq_h = (bf16_t*)d_ws;          // fragment-major weights
    bf16_t* WFq_l = WFq_h + DD * DD;
    bf16_t* WFk_h = WFq_l + DD * DD;
    bf16_t* WFk_l = WFk_h + DD * DD;
    bf16_t* WFv   = WFk_l + DD * DD;
    float*  q2    = (float*)(WFv + DD * DD);
    float*  k2    = q2 + BSR;
    bf16_t* QFh   = (bf16_t*)(k2 + BSR);    // fragment-major Q/K/V
    bf16_t* QFl   = QFh + NROW;
    bf16_t* KFh   = QFl + NROW;
    bf16_t* KFl   = KFh + NROW;
    bf16_t* VF    = KFl + NROW;
    float*  part  = (float*)(VF + NROW);    // TSPLIT x B x H x S x D f32 (128MB)
    unsigned* cnt = (unsigned*)(part + (size_t)TSPLIT * BB * HH * SS * DD);

    float* out = (float*)d_out;

    att_wtrans<<<dim3(49), dim3(256), 0, stream>>>(
        Wq, Wk, Wv, WFq_h, WFq_l, WFk_h, WFk_l, WFv, q2, k2, cnt);

    att_gemm_qkv<<<dim3((BSR / 16) * 4), dim3(256), 0, stream>>>(
        p, e, WFq_h, WFq_l, WFk_h, WFk_l, WFv, QFh, QFl, KFh, KFl, VF, q2, k2);

    att_flash<<<dim3(32 * TSPLIT * BB), dim3(256), 0, stream>>>(
        QFh, QFl, KFh, KFl, VF, q2, k2, gamma, part, cnt, out);
}

// Round 4
// 131.802 us; speedup vs baseline: 1.8175x; 1.8175x over previous
//
#include <hip/hip_runtime.h>
#include <hip/hip_bf16.h>

// Problem: B=2, S=2048, D=256, H=8.
// out[b,h,s,:] = sum_{t<=s} exp( max(d2(s,t),0) / (2*gamma_h - 1e-6) ) * V[b,t,:]
// d2(s,t) = |Q_s|^2 + |K_t|^2 - 2 Q_s.K_t ; Q=p@Wq, K=p@Wk, V=e@Wv.
// Heads with equal gamma produce identical outputs -> dedupe by representative.
//
// R7: all MFMA operands pre-swizzled fragment-major (1KB contiguous b128 runs).
// R8: repack fused into GEMM epilogue; atomics -> split partials + reduce. 136us.
// R9: TSPLIT=8 regressed (+4.6us): occupancy gain ~0, traffic cost real.
// R10: fence-fused reduction regressed (240us): device-scope fences force
//      L2 writeback/invalidate on non-coherent XCD L2s -> flash 155us alone.
//      REVERTED to R8 structure.
// R11: flash is dependent-MFMA-latency bound (MfmaUtil 2%, 24-deep chains,
//      2-way ILP, 1 wave/SIMD).  Process TWO t-tiles per iteration: 4
//      independent score chains, 2 V-sets in flight, 1 barrier per 2 tiles.
//      launch_bounds(256,1) frees VGPR budget (grid=256 -> 1 block/CU anyway).

#define BB   2
#define SS   2048
#define DD   256
#define HH   8
#define BSR  (BB*SS)        // 4096 rows
#define TSPLIT 4

typedef __bf16 bf16_t;
typedef __bf16 bf16x8 __attribute__((ext_vector_type(8)));
typedef float  f32x4  __attribute__((ext_vector_type(4)));

static __device__ __forceinline__ f32x4 mfma16(bf16x8 a, bf16x8 b, f32x4 c) {
    return __builtin_amdgcn_mfma_f32_16x16x32_bf16(a, b, c, 0, 0, 0);
}

// ---------------------------------------------------------------------------
// K0: W -> fragment-major WF (hi/lo split), plus q2/k2 zeroing (block 48).
// WF chunk (g16 in [0,16), kc in [0,8)) holds 512 elems at ((g16*8+kc)*512):
// position u*8+j = W^T[n = g16*16 + (u&15)][k = kc*32 + (u>>4)*8 + j].
// gemm's B-frag load is then base + lane*8 : contiguous 1KB per wave.
// ---------------------------------------------------------------------------
__global__ __launch_bounds__(256) void att_wtrans(
    const float* __restrict__ Wq, const float* __restrict__ Wk,
    const float* __restrict__ Wv,
    bf16_t* __restrict__ WFq_h, bf16_t* __restrict__ WFq_l,
    bf16_t* __restrict__ WFk_h, bf16_t* __restrict__ WFk_l,
    bf16_t* __restrict__ WFv, float* __restrict__ q2, float* __restrict__ k2)
{
    __shared__ float tT[64][68];    // [n_local][k_local], pad 68
    const int tid = threadIdx.x;
    if (blockIdx.x == 48) {         // zero q2/k2 (gemm accumulates atomically)
        for (int i = tid; i < BSR; i += 256) { q2[i] = 0.f; k2[i] = 0.f; }
        return;
    }
    const int mat = blockIdx.x >> 4;        // 0=Wq 1=Wk 2=Wv
    const int tl  = blockIdx.x & 15;
    const int tr  = (tl >> 2) * 64, tc = (tl & 3) * 64;  // k-range, n-range
    const float* W = (mat == 0) ? Wq : ((mat == 1) ? Wk : Wv);

    // load W[k][n] tile rows coalesced, scatter transposed into LDS
#pragma unroll
    for (int i = 0; i < 4; ++i) {
        const int fidx = i * 256 + tid;     // [0,1024) float4 units
        const int r  = fidx >> 4;           // k_local
        const int c4 = fidx & 15;           // n_local/4
        const float4 v = *(const float4*)(W + (size_t)(tr + r) * DD + tc + c4 * 4);
        tT[c4 * 4 + 0][r] = v.x; tT[c4 * 4 + 1][r] = v.y;
        tT[c4 * 4 + 2][r] = v.z; tT[c4 * 4 + 3][r] = v.w;
    }
    __syncthreads();

#pragma unroll
    for (int i = 0; i < 2; ++i) {
        const int uidx  = i * 256 + tid;    // [0,512) 16B units
        const int chunk = uidx >> 6;        // kc_l(2) x c16(4)
        const int kc_l  = chunk >> 2, c16 = chunk & 3;
        const int u = uidx & 63, m16 = u & 15, quad = u >> 4;
        const float* src = &tT[c16 * 16 + m16][kc_l * 32 + quad * 8];
        const float4 a = *(const float4*)src;
        const float4 bq = *(const float4*)(src + 4);
        const float f[8] = {a.x, a.y, a.z, a.w, bq.x, bq.y, bq.z, bq.w};
        bf16x8 hi, lo;
#pragma unroll
        for (int j = 0; j < 8; ++j) {
            const bf16_t h = (bf16_t)f[j];
            hi[j] = h; lo[j] = (bf16_t)(f[j] - (float)h);
        }
        const int g16 = (tc >> 4) + c16;
        const int kcg = (tr >> 5) + kc_l;
        const size_t off = ((size_t)(g16 * 8 + kcg)) * 512 + (size_t)u * 8;
        if (mat == 0)      { *(bf16x8*)(WFq_h + off) = hi; *(bf16x8*)(WFq_l + off) = lo; }
        else if (mat == 1) { *(bf16x8*)(WFk_h + off) = hi; *(bf16x8*)(WFk_l + off) = lo; }
        else               { *(bf16x8*)(WFv + off)  = hi; }
    }
}

// ---------------------------------------------------------------------------
// K1: fused QKV projection via MFMA + DIRECT fragment-major epilogue.
// Block = 256 thr, 16 rows x 64 n-cols (4-way n-split in grid).
// ---------------------------------------------------------------------------
__global__ __launch_bounds__(256, 2) void att_gemm_qkv(
    const float* __restrict__ p, const float* __restrict__ e,
    const bf16_t* __restrict__ WFq_h, const bf16_t* __restrict__ WFq_l,
    const bf16_t* __restrict__ WFk_h, const bf16_t* __restrict__ WFk_l,
    const bf16_t* __restrict__ WFv,
    bf16_t* __restrict__ QFh, bf16_t* __restrict__ QFl,
    bf16_t* __restrict__ KFh, bf16_t* __restrict__ KFl,
    bf16_t* __restrict__ VF, float* __restrict__ q2, float* __restrict__ k2)
{
    __shared__ float pL[16][264];
    __shared__ float eL[16][264];
    __shared__ float fQ[16][68];
    __shared__ float fK[16][68];
    __shared__ float fV[16][68];

    const int tid  = threadIdx.x;
    const int w    = tid >> 6;
    const int lane = tid & 63;
    const int m16  = lane & 15;
    const int quad = lane >> 4;
    const int row0 = (blockIdx.x >> 2) * 16;
    const int nb   = blockIdx.x & 3;

    // stage p/e tiles (16 rows x 256 cols), coalesced
#pragma unroll
    for (int i = 0; i < 4; ++i) {
        const int fidx = i * 256 + tid;     // [0,1024) float4
        const int r  = fidx >> 6;
        const int c4 = fidx & 63;
        const float4 pv = *(const float4*)(p + (size_t)(row0 + r) * DD + c4 * 4);
        const float4 ev = *(const float4*)(e + (size_t)(row0 + r) * DD + c4 * 4);
        *(float4*)&pL[r][c4 * 4] = pv;
        *(float4*)&eL[r][c4 * 4] = ev;
    }
    __syncthreads();

    f32x4 aQ = f32x4{0.f, 0.f, 0.f, 0.f};
    f32x4 aK = f32x4{0.f, 0.f, 0.f, 0.f};
    f32x4 aV = f32x4{0.f, 0.f, 0.f, 0.f};

#pragma unroll 2
    for (int kc = 0; kc < 8; ++kc) {
        const float* ps = &pL[m16][kc * 32 + quad * 8];
        const float* es = &eL[m16][kc * 32 + quad * 8];
        const float4 p0 = *(const float4*)ps;
        const float4 p1 = *(const float4*)(ps + 4);
        const float4 e0 = *(const float4*)es;
        const float4 e1 = *(const float4*)(es + 4);
        const float pa[8] = {p0.x, p0.y, p0.z, p0.w, p1.x, p1.y, p1.z, p1.w};
        const float ea[8] = {e0.x, e0.y, e0.z, e0.w, e1.x, e1.y, e1.z, e1.w};
        bf16x8 aph, apl, aeb;
#pragma unroll
        for (int j = 0; j < 8; ++j) {
            const bf16_t h = (bf16_t)pa[j];
            aph[j] = h;
            apl[j] = (bf16_t)(pa[j] - (float)h);
            aeb[j] = (bf16_t)ea[j];
        }
        const size_t wo = ((size_t)((nb * 4 + w) * 8 + kc)) * 512 + (size_t)lane * 8;
        const bf16x8 bqh = *(const bf16x8*)(WFq_h + wo);
        const bf16x8 bql = *(const bf16x8*)(WFq_l + wo);
        const bf16x8 bkh = *(const bf16x8*)(WFk_h + wo);
        const bf16x8 bkl = *(const bf16x8*)(WFk_l + wo);
        const bf16x8 bv  = *(const bf16x8*)(WFv + wo);
        aQ = mfma16(aph, bqh, aQ);
        aQ = mfma16(apl, bqh, aQ);
        aQ = mfma16(aph, bql, aQ);
        aK = mfma16(aph, bkh, aK);
        aK = mfma16(apl, bkh, aK);
        aK = mfma16(aph, bkl, aK);
        aV = mfma16(aeb, bv, aV);
    }

    // stage accumulators f32 into LDS for the fragment transpose
#pragma unroll
    for (int r = 0; r < 4; ++r) {
        const int rl = quad * 4 + r;          // C/D row = quad*4+reg
        fQ[rl][w * 16 + m16] = aQ[r];
        fK[rl][w * 16 + m16] = aK[r];
        fV[rl][w * 16 + m16] = aV[r];
    }

    // q2/k2 row-norm partials (from f32 accumulators)
#pragma unroll
    for (int r = 0; r < 4; ++r) {
        float vq = aQ[r] * aQ[r], vk = aK[r] * aK[r];
#pragma unroll
        for (int off = 8; off >= 1; off >>= 1) {
            vq += __shfl_xor(vq, off);
            vk += __shfl_xor(vk, off);
        }
        if (m16 == 0) {
            atomicAdd(q2 + row0 + quad * 4 + r, vq);
            atomicAdd(k2 + row0 + quad * 4 + r, vk);
        }
    }

    __syncthreads();

    const int b   = row0 >> 11;
    const int sl  = row0 & 2047;
    const int tt  = sl >> 6;
    const int st  = sl >> 5;
    const int w4  = (sl >> 4) & 3;   // KF row-group
    const int mt  = (sl >> 4) & 1;   // QF row-group
    const int kc2 = (sl >> 5) & 1;   // VF t-half
    const int uh  = (sl >> 4) & 1;   // VF u-half

    if (w < 2) {
        // QF chunk kc = nb*2 + w  (hi + lo)
        const int cl = w;
        const float* src = &fQ[m16][cl * 32 + quad * 8];
        const float4 a = *(const float4*)src;
        const float4 c = *(const float4*)(src + 4);
        const float f[8] = {a.x, a.y, a.z, a.w, c.x, c.y, c.z, c.w};
        bf16x8 hi, lo;
#pragma unroll
        for (int j = 0; j < 8; ++j) {
            const bf16_t h = (bf16_t)f[j];
            hi[j] = h; lo[j] = (bf16_t)(f[j] - (float)h);
        }
        const size_t off = ((size_t)(b * 64 + st)) * 8192
                         + (size_t)(mt * 8 + nb * 2 + cl) * 512 + (size_t)lane * 8;
        *(bf16x8*)(QFh + off) = hi; *(bf16x8*)(QFl + off) = lo;
    } else {
        // KF chunk kc = nb*2 + (w-2)  (hi + lo)
        const int cl = w - 2;
        const float* src = &fK[m16][cl * 32 + quad * 8];
        const float4 a = *(const float4*)src;
        const float4 c = *(const float4*)(src + 4);
        const float f[8] = {a.x, a.y, a.z, a.w, c.x, c.y, c.z, c.w};
        bf16x8 hi, lo;
#pragma unroll
        for (int j = 0; j < 8; ++j) {
            const bf16_t h = (bf16_t)f[j];
            hi[j] = h; lo[j] = (bf16_t)(f[j] - (float)h);
        }
        const size_t off = ((size_t)(b * 32 + tt)) * 16384
                         + (size_t)(w4 * 8 + nb * 2 + cl) * 512 + (size_t)lane * 8;
        *(bf16x8*)(KFh + off) = hi; *(bf16x8*)(KFl + off) = lo;
    }

    // VF half-chunks: wave w handles nt=w with lanes 0..31 (u-half uh)
    if (lane < 32) {
        const int nt  = w;
        const int u   = uh * 32 + lane;
        const int tl0 = (lane >> 4) * 8;     // t_local base within block rows
        bf16x8 vb;
#pragma unroll
        for (int j = 0; j < 8; ++j)
            vb[j] = (bf16_t)fV[tl0 + j][nt * 16 + (lane & 15)];
        const size_t off = ((size_t)(b * 32 + tt)) * 16384
                         + (size_t)(nb * 8 + kc2 * 4 + nt) * 512 + (size_t)u * 8;
        *(bf16x8*)(VF + off) = vb;
    }
}

// ---------------------------------------------------------------------------
// K2: flash-style causal pass, triangle-paired, fragment-major operands.
// Grid = 256 blocks (32 pairs x 4 splits x 2 b), bid&7 == split*2+b so each
// XCD hosts one (split,b) class (K/V set ~384KB fits its 4MiB L2).
// R11: TWO t-tiles per inner iteration -> 4 independent score-MFMA chains,
// both V-sets prefetched, one barrier per 2 tiles.  Single-tile tail path.
// split 0 stores straight to out[b][rep]; splits 1..3 store to ws partials.
// ---------------------------------------------------------------------------
__global__ __launch_bounds__(256, 1) void att_flash(
    const bf16_t* __restrict__ QFh, const bf16_t* __restrict__ QFl,
    const bf16_t* __restrict__ KFh, const bf16_t* __restrict__ KFl,
    const bf16_t* __restrict__ VF, const float* __restrict__ q2,
    const float* __restrict__ k2, const float* __restrict__ gamma,
    float* __restrict__ part, float* __restrict__ out)
{
    __shared__ bf16_t Pb[2][2][32][72];   // [parity][tile-in-pair][s][t]

    const int tid   = threadIdx.x;
    const int pair  = blockIdx.x >> 3;     // 0..31
    const int sub   = blockIdx.x & 7;      // == xcd class
    const int split = sub >> 1;            // 0..3
    const int b     = sub & 1;
    const int wave  = tid >> 6;
    const int lane  = tid & 63;
    const int m16   = lane & 15;
    const int quad  = lane >> 4;

    float g[8];
#pragma unroll
    for (int h = 0; h < 8; ++h) g[h] = gamma[h];

    int q = 0;

    for (int half = 0; half < 2; ++half) {
        const int st = half ? (63 - pair) : pair;
        const int s0 = st * 32;

        // Q fragments -> registers, contiguous chunk loads.
        bf16x8 aQh[2][8], aQl[2][8];
        const size_t qtile = ((size_t)(b * 64 + st)) * 8192 + (size_t)lane * 8;
#pragma unroll
        for (int mt = 0; mt < 2; ++mt)
#pragma unroll
            for (int kc = 0; kc < 8; ++kc) {
                const size_t base = qtile + (size_t)(mt * 8 + kc) * 512;
                aQh[mt][kc] = *(const bf16x8*)(QFh + base);
                aQl[mt][kc] = *(const bf16x8*)(QFl + base);
            }

        float q2r[2][4];
#pragma unroll
        for (int mt = 0; mt < 2; ++mt)
#pragma unroll
            for (int r = 0; r < 4; ++r)
                q2r[mt][r] = q2[b * SS + s0 + mt * 16 + quad * 4 + r];

        const int n_tiles = (s0 + 31) / 64 + 1;

        for (int h = 0; h < HH; ++h) {
            int rep = 0;
            while (g[rep] != g[h]) ++rep;
            if (rep != h) continue;
            const float cexp = 1.0f / (2.0f * g[h] - 1e-6f);

            f32x4 O[2][4];
#pragma unroll
            for (int mt = 0; mt < 2; ++mt)
#pragma unroll
                for (int nt = 0; nt < 4; ++nt)
                    O[mt][nt] = f32x4{0.f, 0.f, 0.f, 0.f};

            int ti = split;

            // ---- dual-tile iterations: tiles ti and ti+TSPLIT together ----
            while (ti + TSPLIT < n_tiles) {
                const int tiA = ti, tiB = ti + TSPLIT;
                const int tgA = tiA * 64 + wave * 16 + m16;
                const int tgB = tiB * 64 + wave * 16 + m16;
                const size_t tileA = ((size_t)(b * 32 + tiA)) * 16384
                                   + (size_t)wave * 4096 + (size_t)lane * 8;
                const size_t tileB = ((size_t)(b * 32 + tiB)) * 16384
                                   + (size_t)wave * 4096 + (size_t)lane * 8;

                // V prefetch for both tiles (overlaps scores + barrier)
                bf16x8 vfA[2][4], vfB[2][4];
#pragma unroll
                for (int kc2 = 0; kc2 < 2; ++kc2)
#pragma unroll
                    for (int nt = 0; nt < 4; ++nt) {
                        vfA[kc2][nt] = *(const bf16x8*)(
                            VF + tileA + (size_t)(kc2 * 4 + nt) * 512);
                        vfB[kc2][nt] = *(const bf16x8*)(
                            VF + tileB + (size_t)(kc2 * 4 + nt) * 512);
                    }
                const float k2A = k2[b * SS + tgA];
                const float k2B = k2[b * SS + tgB];

                // scores: 4 independent accumulator chains (2 tiles x 2 mt)
                f32x4 aA0 = f32x4{0.f, 0.f, 0.f, 0.f};
                f32x4 aA1 = f32x4{0.f, 0.f, 0.f, 0.f};
                f32x4 aB0 = f32x4{0.f, 0.f, 0.f, 0.f};
                f32x4 aB1 = f32x4{0.f, 0.f, 0.f, 0.f};
#pragma unroll
                for (int kc = 0; kc < 8; ++kc) {
                    const bf16x8 bhA = *(const bf16x8*)(KFh + tileA + (size_t)kc * 512);
                    const bf16x8 blA = *(const bf16x8*)(KFl + tileA + (size_t)kc * 512);
                    const bf16x8 bhB = *(const bf16x8*)(KFh + tileB + (size_t)kc * 512);
                    const bf16x8 blB = *(const bf16x8*)(KFl + tileB + (size_t)kc * 512);
                    aA0 = mfma16(aQh[0][kc], bhA, aA0);
                    aA1 = mfma16(aQh[1][kc], bhA, aA1);
                    aB0 = mfma16(aQh[0][kc], bhB, aB0);
                    aB1 = mfma16(aQh[1][kc], bhB, aB1);
                    aA0 = mfma16(aQl[0][kc], bhA, aA0);
                    aA1 = mfma16(aQl[1][kc], bhA, aA1);
                    aB0 = mfma16(aQl[0][kc], bhB, aB0);
                    aB1 = mfma16(aQl[1][kc], bhB, aB1);
                    aA0 = mfma16(aQh[0][kc], blA, aA0);
                    aA1 = mfma16(aQh[1][kc], blA, aA1);
                    aB0 = mfma16(aQh[0][kc], blB, aB0);
                    aB1 = mfma16(aQh[1][kc], blB, aB1);
                }

#pragma unroll
                for (int mt = 0; mt < 2; ++mt) {
#pragma unroll
                    for (int r = 0; r < 4; ++r) {
                        const int sl = mt * 16 + quad * 4 + r;
                        const int sg = s0 + sl;
                        float dA = q2r[mt][r] + k2A
                                 - 2.0f * (mt ? aA1[r] : aA0[r]);
                        dA = fmaxf(dA, 0.0f);
                        const float wA = (tgA <= sg) ? __expf(cexp * dA) : 0.0f;
                        Pb[q][0][sl][wave * 16 + m16] = (bf16_t)wA;
                        float dB = q2r[mt][r] + k2B
                                 - 2.0f * (mt ? aB1[r] : aB0[r]);
                        dB = fmaxf(dB, 0.0f);
                        const float wB = (tgB <= sg) ? __expf(cexp * dB) : 0.0f;
                        Pb[q][1][sl][wave * 16 + m16] = (bf16_t)wB;
                    }
                }
                __syncthreads();

                // PV: tile A fully first, then tile B (same add order as R8)
#pragma unroll
                for (int kc2 = 0; kc2 < 2; ++kc2) {
                    const bf16x8 pa0 = *(const bf16x8*)&Pb[q][0][m16][kc2 * 32 + quad * 8];
                    const bf16x8 pa1 = *(const bf16x8*)&Pb[q][0][m16 + 16][kc2 * 32 + quad * 8];
#pragma unroll
                    for (int nt = 0; nt < 4; ++nt) {
                        O[0][nt] = mfma16(pa0, vfA[kc2][nt], O[0][nt]);
                        O[1][nt] = mfma16(pa1, vfA[kc2][nt], O[1][nt]);
                    }
                }
#pragma unroll
                for (int kc2 = 0; kc2 < 2; ++kc2) {
                    const bf16x8 pb0 = *(const bf16x8*)&Pb[q][1][m16][kc2 * 32 + quad * 8];
                    const bf16x8 pb1 = *(const bf16x8*)&Pb[q][1][m16 + 16][kc2 * 32 + quad * 8];
#pragma unroll
                    for (int nt = 0; nt < 4; ++nt) {
                        O[0][nt] = mfma16(pb0, vfB[kc2][nt], O[0][nt]);
                        O[1][nt] = mfma16(pb1, vfB[kc2][nt], O[1][nt]);
                    }
                }
                q ^= 1;
                ti += 2 * TSPLIT;
            }

            // ---- single-tile tail (at most one) ----
            if (ti < n_tiles) {
                const int tg = ti * 64 + wave * 16 + m16;
                const size_t tile = ((size_t)(b * 32 + ti)) * 16384
                                  + (size_t)wave * 4096 + (size_t)lane * 8;

                bf16x8 vf[2][4];
#pragma unroll
                for (int kc2 = 0; kc2 < 2; ++kc2)
#pragma unroll
                    for (int nt = 0; nt < 4; ++nt)
                        vf[kc2][nt] = *(const bf16x8*)(
                            VF + tile + (size_t)(kc2 * 4 + nt) * 512);
                const float k2v = k2[b * SS + tg];

                f32x4 acc0 = f32x4{0.f, 0.f, 0.f, 0.f};
                f32x4 acc1 = f32x4{0.f, 0.f, 0.f, 0.f};
#pragma unroll
                for (int kc = 0; kc < 8; ++kc) {
                    const bf16x8 bh = *(const bf16x8*)(KFh + tile + (size_t)kc * 512);
                    const bf16x8 bl = *(const bf16x8*)(KFl + tile + (size_t)kc * 512);
                    acc0 = mfma16(aQh[0][kc], bh, acc0);
                    acc1 = mfma16(aQh[1][kc], bh, acc1);
                    acc0 = mfma16(aQl[0][kc], bh, acc0);
                    acc1 = mfma16(aQl[1][kc], bh, acc1);
                    acc0 = mfma16(aQh[0][kc], bl, acc0);
                    acc1 = mfma16(aQh[1][kc], bl, acc1);
                }

#pragma unroll
                for (int mt = 0; mt < 2; ++mt) {
#pragma unroll
                    for (int r = 0; r < 4; ++r) {
                        const int sl = mt * 16 + quad * 4 + r;
                        const int sg = s0 + sl;
                        const float dotv = mt ? acc1[r] : acc0[r];
                        float d2 = q2r[mt][r] + k2v - 2.0f * dotv;
                        d2 = fmaxf(d2, 0.0f);
                        const float wgt = (tg <= sg) ? __expf(cexp * d2) : 0.0f;
                        Pb[q][0][sl][wave * 16 + m16] = (bf16_t)wgt;
                    }
                }
                __syncthreads();

#pragma unroll
                for (int kc2 = 0; kc2 < 2; ++kc2) {
                    const bf16x8 pa0 = *(const bf16x8*)&Pb[q][0][m16][kc2 * 32 + quad * 8];
                    const bf16x8 pa1 = *(const bf16x8*)&Pb[q][0][m16 + 16][kc2 * 32 + quad * 8];
#pragma unroll
                    for (int nt = 0; nt < 4; ++nt) {
                        O[0][nt] = mfma16(pa0, vf[kc2][nt], O[0][nt]);
                        O[1][nt] = mfma16(pa1, vf[kc2][nt], O[1][nt]);
                    }
                }
                q ^= 1;
            }

            // plain stores: split0 -> out slab, splits 1..3 -> ws partials
            float* dst = (split == 0)
                ? out  + (((size_t)b * HH + h) * SS + s0) * DD
                : part + ((((size_t)(split - 1) * BB + b) * HH + h) * SS + s0) * DD;
#pragma unroll
            for (int mt = 0; mt < 2; ++mt)
#pragma unroll
                for (int nt = 0; nt < 4; ++nt)
#pragma unroll
                    for (int r = 0; r < 4; ++r)
                        dst[(size_t)(mt * 16 + quad * 4 + r) * DD
                            + wave * 64 + nt * 16 + m16] = O[mt][nt][r];
        }
    }
}

// ---------------------------------------------------------------------------
// K3: reduce split partials into rep heads and broadcast to duplicate-gamma
// heads.  out[b][rep] already holds split0; add 3 partial slabs, write to
// every head sharing that gamma.
// ---------------------------------------------------------------------------
__global__ __launch_bounds__(256) void att_reduce_bcast(
    const float* __restrict__ gamma, const float* __restrict__ part,
    float* __restrict__ out)
{
    const int j = blockIdx.x * 256 + threadIdx.x;   // float4 index within slab
    const int b = blockIdx.y;
    const int slab = SS * DD / 4;

    float g[8];
#pragma unroll
    for (int h = 0; h < 8; ++h) g[h] = gamma[h];

    const float4* pp = (const float4*)part;
    float4* o4 = (float4*)out;

    float4 repval{0.f, 0.f, 0.f, 0.f};
    int last_rep = -1;
#pragma unroll
    for (int h = 0; h < HH; ++h) {
        int rep = 0;
        while (g[rep] != g[h]) ++rep;
        float4* o = o4 + ((size_t)(b * HH + h)) * slab + j;
        if (rep == h) {
            float4 v = *o;
#pragma unroll
            for (int k = 0; k < TSPLIT - 1; ++k) {
                const float4 pv = pp[(((size_t)k * BB + b) * HH + h) * slab + j];
                v.x += pv.x; v.y += pv.y; v.z += pv.z; v.w += pv.w;
            }
            *o = v; repval = v; last_rep = h;
        } else {
            if (last_rep != rep) {
                repval = o4[((size_t)(b * HH + rep)) * slab + j];
                last_rep = rep;
            }
            *o = repval;
        }
    }
}

extern "C" void kernel_launch(void* const* d_in, const int* in_sizes, int n_in,
                              void* d_out, int out_size, void* d_ws, size_t ws_size,
                              hipStream_t stream) {
    (void)in_sizes; (void)n_in; (void)out_size; (void)ws_size;
    // inputs: 0=x (unused), 1=e, 2=p, 3=W_q, 4=W_k, 5=W_v, 6=gamma
    const float* e     = (const float*)d_in[1];
    const float* p     = (const float*)d_in[2];
    const float* Wq    = (const float*)d_in[3];
    const float* Wk    = (const float*)d_in[4];
    const float* Wv    = (const float*)d_in[5];
    const float* gamma = (const float*)d_in[6];

    const size_t NROW = (size_t)BSR * DD;   // 1048576 elements
    bf16_t* WFq_h = (bf16_t*)d_ws;          // fragment-major weights
    bf16_t* WFq_l = WFq_h + DD * DD;
    bf16_t* WFk_h = WFq_l + DD * DD;
    bf16_t* WFk_l = WFk_h + DD * DD;
    bf16_t* WFv   = WFk_l + DD * DD;
    float*  q2    = (float*)(WFv + DD * DD);
    float*  k2    = q2 + BSR;
    bf16_t* QFh   = (bf16_t*)(k2 + BSR);    // fragment-major Q/K/V
    bf16_t* QFl   = QFh + NROW;
    bf16_t* KFh   = QFl + NROW;
    bf16_t* KFl   = KFh + NROW;
    bf16_t* VF    = KFl + NROW;
    float*  part  = (float*)(VF + NROW);    // 3 x B x H x S x D f32 (~101MB)

    float* out = (float*)d_out;

    att_wtrans<<<dim3(49), dim3(256), 0, stream>>>(
        Wq, Wk, Wv, WFq_h, WFq_l, WFk_h, WFk_l, WFv, q2, k2);

    att_gemm_qkv<<<dim3((BSR / 16) * 4), dim3(256), 0, stream>>>(
        p, e, WFq_h, WFq_l, WFk_h, WFk_l, WFv, QFh, QFl, KFh, KFl, VF, q2, k2);

    att_flash<<<dim3(32 * TSPLIT * BB), dim3(256), 0, stream>>>(
        QFh, QFl, KFh, KFl, VF, q2, k2, gamma, part, out);

    att_reduce_bcast<<<dim3(SS * DD / 4 / 256, BB), dim3(256), 0, stream>>>(
        gamma, part, out);
}